// Round 11
// baseline (122.078 us; speedup 1.0000x reference)
//
#include <hip/hip_runtime.h>

typedef unsigned short u16t;
typedef unsigned int u32t;
typedef __bf16 bf16x8 __attribute__((ext_vector_type(8)));
typedef float f32x4 __attribute__((ext_vector_type(4)));
typedef float f32x16 __attribute__((ext_vector_type(16)));
typedef unsigned int u32x4 __attribute__((ext_vector_type(4)));
typedef unsigned int u32x2 __attribute__((ext_vector_type(2)));

#define DEV static __device__ __forceinline__

DEV u16t f2bf(float f){
  u32t u = __builtin_bit_cast(u32t, f);
  u += 0x7fffu + ((u >> 16) & 1u);   // RNE
  return (u16t)(u >> 16);
}

DEV u32t cvtpk(float lo, float hi){
  u32t r;
  asm("v_cvt_pk_bf16_f32 %0, %1, %2" : "=v"(r) : "v"(lo), "v"(hi));
  return r;
}

// v_permlane32_swap_b32: a.hi32lanes <-> b.lo32lanes
DEV void plswap(u32t &a, u32t &b){
  asm("v_permlane32_swap_b32 %0, %1" : "+v"(a), "+v"(b));
}

DEV float fexp2(float x){
#if __has_builtin(__builtin_amdgcn_exp2f)
  return __builtin_amdgcn_exp2f(x);
#else
  return exp2f(x);
#endif
}

DEV void gll16(const void* g, void* l){
  __builtin_amdgcn_global_load_lds((const __attribute__((address_space(1))) void*)g,
                                   (__attribute__((address_space(3))) void*)l, 16, 0, 0);
}

DEV f32x4 mfma16(bf16x8 a, bf16x8 b, f32x4 c){
  return __builtin_amdgcn_mfma_f32_16x16x32_bf16(a, b, c, 0, 0, 0);
}

DEV f32x16 mfma32(bf16x8 a, bf16x8 b, f32x16 c){
  return __builtin_amdgcn_mfma_f32_32x32x16_bf16(a, b, c, 0, 0, 0);
}

// ---------------- cast x: fp32 -> bf16 ----------------
__global__ __launch_bounds__(256) void k_cast_x(const float4* __restrict__ x, u16t* __restrict__ xb){
  int idx = blockIdx.x * 256 + threadIdx.x;
  float4 v = x[idx];
  ushort4 o = make_ushort4(f2bf(v.x), f2bf(v.y), f2bf(v.z), f2bf(v.w));
  *(ushort4*)&xb[idx * 4] = o;
}

// ---------------- cast weights; fold 0.125*log2(e) into Wq ----------------
__global__ __launch_bounds__(256) void k_cast_w(const float* __restrict__ Wq, const float* __restrict__ Wk,
                         const float* __restrict__ Wv, const float* __restrict__ Wp,
                         u16t* __restrict__ wqkv, u16t* __restrict__ wp){
  int idx = blockIdx.x * 256 + threadIdx.x;  // 0..262143
  if (idx < 196608){
    float v;
    if (idx < 65536)        v = Wq[idx] * 0.1803368801f;   // 0.125 * log2(e)
    else if (idx < 131072)  v = Wk[idx - 65536];
    else                    v = Wv[idx - 131072];
    wqkv[idx] = f2bf(v);
  } else {
    int j = idx - 196608;
    wp[j] = f2bf(Wp[j]);
  }
}

// ---------------- bf16 GEMM: out[m,n] = sum_k A[m,k]*W[n,k] ----------------
// BM=128, BN=64, BK=64, 4 waves (2x2). LDS 16B-chunk XOR swizzle.
// QKV epilogue: Q -> row-major [bh][n][64];
//   K -> flash A-frag slots: [bh][nt 64][kk*2+jt][hi*32+p] x 16B (slot = K[jt*32+p][kk*16+8hi..+8])
//   V -> i-major tiles [bh][nt][8 i][64 d] x 16B (slot = V^T[d][8i..8i+8])
// Both K and V flash staging sources become perfectly LINEAR.
template<bool IS_QKV>
__global__ __launch_bounds__(256) void k_gemm(const u16t* __restrict__ A, const u16t* __restrict__ W,
    const float* __restrict__ bias, u16t* __restrict__ oq, u16t* __restrict__ okk, u16t* __restrict__ vtg,
    float* __restrict__ op, int Ntot){
  __shared__ u32x4 sm[1536];
  const int tid = threadIdx.x, lane = tid & 63, w = tid >> 6, g = lane >> 4, li = lane & 15;
  const int m0 = blockIdx.x * 128, n0 = blockIdx.y * 64;
  const int wm = w >> 1, wn = w & 1;
  f32x4 acc[4][2] = {};
  for (int kk = 0; kk < 4; ++kk){
    #pragma unroll
    for (int rnd = 0; rnd < 4; ++rnd){
      int cid = rnd * 256 + tid;
      int row = cid >> 3, ch = cid & 7;
      const u16t* src = A + (m0 + row) * 256 + kk * 64 + ((ch ^ (row & 7)) << 3);
      gll16(src, (char*)sm + (rnd * 256 + w * 64) * 16);
    }
    #pragma unroll
    for (int rnd = 0; rnd < 2; ++rnd){
      int cid = rnd * 256 + tid;
      int row = cid >> 3, ch = cid & 7;
      const u16t* src = W + (n0 + row) * 256 + kk * 64 + ((ch ^ (row & 7)) << 3);
      gll16(src, (char*)sm + 16384 + (rnd * 256 + w * 64) * 16);
    }
    __syncthreads();
    #pragma unroll
    for (int ks = 0; ks < 2; ++ks){
      bf16x8 bfr[2];
      #pragma unroll
      for (int nj = 0; nj < 2; ++nj){
        int row = wn * 32 + nj * 16 + li;
        bfr[nj] = __builtin_bit_cast(bf16x8, sm[1024 + row * 8 + ((ks * 4 + g) ^ (row & 7))]);
      }
      #pragma unroll
      for (int mi = 0; mi < 4; ++mi){
        int row = wm * 64 + mi * 16 + li;
        bf16x8 af = __builtin_bit_cast(bf16x8, sm[row * 8 + ((ks * 4 + g) ^ (row & 7))]);
        #pragma unroll
        for (int nj = 0; nj < 2; ++nj)
          acc[mi][nj] = mfma16(af, bfr[nj], acc[mi][nj]);
      }
    }
    __syncthreads();
  }
  if (IS_QKV){
    const int which = n0 >> 8, h = (n0 >> 6) & 3;
    if (which == 2){
      // transpose V within block via LDS (vt[64 d][128 kv-local], chunk-XOR swizzled),
      // then store i-major tiles
      u16t* smv = (u16t*)sm;
      #pragma unroll
      for (int mi = 0; mi < 4; ++mi){
        #pragma unroll
        for (int nj = 0; nj < 2; ++nj){
          int d = wn * 32 + nj * 16 + li;
          int mloc = wm * 64 + mi * 16 + g * 4;
          u32x2 pk2;
          pk2.x = cvtpk(acc[mi][nj][0], acc[mi][nj][1]);
          pk2.y = cvtpk(acc[mi][nj][2], acc[mi][nj][3]);
          int chk = mloc >> 3, inner = (mloc & 7) * 2;
          *(u32x2*)((char*)smv + d * 256 + (((chk ^ (d & 7))) << 4) + inner) = pk2;
        }
      }
      __syncthreads();
      const int b = m0 >> 12, bh2 = b * 4 + h, mbase = m0 & 4095;
      #pragma unroll
      for (int rnd = 0; rnd < 4; ++rnd){
        int qq = rnd * 256 + tid;       // 0..1023
        int d = qq & 63, cidx = qq >> 6;              // cidx 0..15 (8 kv each)
        u32x4 val = *(const u32x4*)((char*)smv + d * 256 + ((cidx ^ (d & 7)) << 4));
        int nt = (mbase >> 6) + (cidx >> 3), i = cidx & 7;
        *(u32x4*)((char*)vtg + ((((size_t)bh2 * 64 + nt) * 8 + i) * 64 + d) * 16) = val;
      }
    } else if (which == 1){
      // K: flash A-frag slot layout
      #pragma unroll
      for (int mi = 0; mi < 4; ++mi){
        int m = m0 + wm * 64 + mi * 16 + g * 4;
        int b = m >> 12;
        #pragma unroll
        for (int nj = 0; nj < 2; ++nj){
          int d = wn * 32 + nj * 16 + li;
          int kk2 = d >> 4, dhi = (d >> 3) & 1, e = d & 7;
          #pragma unroll
          for (int r = 0; r < 4; ++r){
            int row = (m + r) & 4095;
            int nt = row >> 6, jt = (row >> 5) & 1, pp = row & 31;
            okk[(size_t)(b * 4 + h) * 262144 + nt * 4096 + (kk2 * 2 + jt) * 512 + dhi * 256 + pp * 8 + e]
              = f2bf(acc[mi][nj][r]);
          }
        }
      }
    } else {
      // Q: row-major
      #pragma unroll
      for (int mi = 0; mi < 4; ++mi){
        int m = m0 + wm * 64 + mi * 16 + g * 4;
        int b = m >> 12, nn = m & 4095;
        #pragma unroll
        for (int nj = 0; nj < 2; ++nj){
          int d = wn * 32 + nj * 16 + li;
          #pragma unroll
          for (int r = 0; r < 4; ++r)
            oq[((b * 4 + h) * 4096 + nn + r) * 64 + d] = f2bf(acc[mi][nj][r]);
        }
      }
    }
  } else {
    #pragma unroll
    for (int mi = 0; mi < 4; ++mi){
      int m = m0 + wm * 64 + mi * 16 + g * 4;
      #pragma unroll
      for (int nj = 0; nj < 2; ++nj){
        int n = n0 + wn * 32 + nj * 16 + li;
        float bv = bias[n];
        #pragma unroll
        for (int r = 0; r < 4; ++r)
          op[(m + r) * Ntot + n] = acc[mi][nj][r] + bv;
      }
    }
  }
}

// ---------------- flash attention: shared-KV 4-wave blocks, double-buffered, no merge ----------------
// 512 blocks = 16 bh x 32 q-tiles(128 rows); 4 waves each own 32 q-rows, ALL sweep the
// full KV (64 tiles of 64 rows) from SHARED double-buffered LDS (2 x (K 8KB + V 8KB)).
// Staged bytes per wave-iter: 4KB (was 16KB). All staging sources LINEAR (K in A-frag
// slot order, V i-major). m201 discipline: raw s_barrier + counted vmcnt(4); per-thread
// queue = [tile t x4][tile t+1 x4]. Zero bank conflicts in the main loop. No merge.
__global__ __launch_bounds__(256) void k_flash(const u16t* __restrict__ q,
    const u16t* __restrict__ kslot, const u16t* __restrict__ vslot, u16t* __restrict__ ao){
  __shared__ char sm[32768];   // buf c: K @ c*16384 (8KB), V @ +8192 (8KB)
  const int tid = threadIdx.x, lane = tid & 63, w = tid >> 6;
  const int hi = lane >> 5, p = lane & 31;
  const int bid = blockIdx.x;
  const int swz = (bid & 7) * 64 + (bid >> 3);    // XCD-aware, bijective (512%8==0)
  const int bh = swz >> 5, qt = swz & 31;
  const int rowbase = qt * 128 + w * 32;
  const char* kbB = (const char*)kslot + (size_t)bh * 524288 + tid * 16;
  const char* vbB = (const char*)vslot + (size_t)bh * 524288 + tid * 16;

  auto stage = [&](int t, int c){
    char* dst = sm + c * 16384 + tid * 16;
    const char* sK = kbB + (size_t)t * 8192;
    const char* sV = vbB + (size_t)t * 8192;
    gll16(sK, dst);
    gll16(sK + 4096, dst + 4096);
    gll16(sV, dst + 8192);
    gll16(sV + 4096, dst + 12288);
  };

  // Q B-frags: qf[kk] = Q[rowbase+p][k=kk*16+8hi+e]
  u32x4 qf[4];
  #pragma unroll
  for (int kk = 0; kk < 4; ++kk)
    qf[kk] = *(const u32x4*)&q[((size_t)bh * 4096 + rowbase + p) * 64 + kk * 16 + hi * 8];
  asm volatile("s_waitcnt vmcnt(0)" ::: "memory");   // clean queue: only gll16 from here
  stage(0, 0);
  stage(1, 1);

  f32x16 ot[2] = {};         // [dt] O^T accum (rows d, cols i=p)
  float lsp[4] = {};
  const f32x16 fz = {};

  #pragma unroll 1
  for (int t = 0; t < 64; ++t){
    asm volatile("s_waitcnt vmcnt(4)" ::: "memory"); // my 4 loads of tile t landed
    __builtin_amdgcn_s_barrier();                    // => everyone's tile-t loads landed
    asm volatile("" ::: "memory");
    const char* Kb = sm + (t & 1) * 16384;
    const char* Vt = Kb + 8192;
    // ---- QK: S^T[j=0..63][i=p] ----
    f32x16 st[2];
    #pragma unroll
    for (int kk = 0; kk < 4; ++kk)
      #pragma unroll
      for (int jt = 0; jt < 2; ++jt){
        bf16x8 kf = __builtin_bit_cast(bf16x8,
            *(const u32x4*)(Kb + (kk * 2 + jt) * 1024 + lane * 16));
        st[jt] = mfma32(kf, __builtin_bit_cast(bf16x8, qf[kk]), kk == 0 ? fz : st[jt]);
      }
    // ---- per jt: exp2 + lsum + pack + PV ----
    #pragma unroll
    for (int jt = 0; jt < 2; ++jt){
      float e[16];
      #pragma unroll
      for (int r = 0; r < 16; ++r)
        e[r] = fexp2(st[jt][r]);
      #pragma unroll
      for (int r = 0; r < 16; ++r)
        lsp[r & 3] += e[r];
      u32x4 pf[2];
      #pragma unroll
      for (int s = 0; s < 2; ++s){
        u32t a0 = cvtpk(e[s*8+0], e[s*8+1]);
        u32t a1 = cvtpk(e[s*8+2], e[s*8+3]);
        u32t b0 = cvtpk(e[s*8+4], e[s*8+5]);
        u32t b1 = cvtpk(e[s*8+6], e[s*8+7]);
        plswap(a0, b0);
        plswap(a1, b1);
        pf[s] = (u32x4){a0, a1, b0, b1};
      }
      #pragma unroll
      for (int s = 0; s < 2; ++s)
        #pragma unroll
        for (int dt = 0; dt < 2; ++dt){
          bf16x8 vf = __builtin_bit_cast(bf16x8,
              *(const u32x4*)(Vt + ((jt * 2 + s) * 2 + hi) * 1024 + dt * 512 + p * 16));
          ot[dt] = mfma32(vf, __builtin_bit_cast(bf16x8, pf[s]), ot[dt]);
        }
    }
    asm volatile("s_waitcnt lgkmcnt(0)" ::: "memory"); // all my LDS reads of tile t retired
    __builtin_amdgcn_s_barrier();                      // => everyone done reading tile t
    asm volatile("" ::: "memory");
    stage((t + 2) & 63, t & 1);                        // overwrite the buffer just consumed
  }
  asm volatile("s_waitcnt vmcnt(0)" ::: "memory");     // drain tail dummy stages
  __builtin_amdgcn_s_barrier();                        // before reusing buf0 LDS
  asm volatile("" ::: "memory");

  // lsum: lane (p,hi) summed its j-subset; fold hi-halves -> full row-sum for i=p
  float l = (lsp[0] + lsp[1]) + (lsp[2] + lsp[3]);
  l += __shfl_xor(l, 32);
  float inv = __builtin_amdgcn_rcpf(l);

  // per-wave transpose O^T -> row-major via own 4KB region (bf16 [32 i][64 d], XOR-swizzled)
  char* reg = sm + w * 4096;
  #pragma unroll
  for (int dt = 0; dt < 2; ++dt)
    #pragma unroll
    for (int k = 0; k < 8; ++k){
      int d0 = ((2 * k) & 3) + 8 * (k >> 1) + 4 * hi + 32 * dt;
      u32t pkv = cvtpk(ot[dt][2 * k] * inv, ot[dt][2 * k + 1] * inv);
      int ch = d0 >> 3, inner = (d0 & 7) * 2;
      *(u32t*)(reg + p * 128 + ((ch ^ (p & 7)) << 4) + inner) = pkv;
    }
  // read back own region (per-wave, no barrier needed) and store coalesced
  {
    const int b = bh >> 2, h = bh & 3;
    int row = lane >> 1, half = lane & 1;
    const char* src = sm + w * 4096 + row * 128;
    u16t* dst = ao + ((size_t)b * 4096 + rowbase + row) * 256 + h * 64 + half * 32;
    #pragma unroll
    for (int j = 0; j < 4; ++j){
      int ch = half * 4 + j;
      u32x4 v = *(const u32x4*)(src + ((ch ^ (row & 7)) << 4));
      *(u32x4*)(dst + j * 8) = v;
    }
  }
}

extern "C" void kernel_launch(void* const* d_in, const int* in_sizes, int n_in,
                              void* d_out, int out_size, void* d_ws, size_t ws_size,
                              hipStream_t stream){
  (void)in_sizes; (void)n_in; (void)out_size; (void)ws_size;
  const float* x  = (const float*)d_in[0];
  const float* Wq = (const float*)d_in[1];
  const float* Wk = (const float*)d_in[2];
  const float* Wv = (const float*)d_in[3];
  const float* Wp = (const float*)d_in[4];
  const float* bp = (const float*)d_in[5];
  float* out = (float*)d_out;

  u16t* ws   = (u16t*)d_ws;
  u16t* xb   = ws;                       // [16384][256] bf16 x
  u16t* qg   = ws + 4194304;             // [16 bh][4096][64] Q row-major
  u16t* kg   = ws + 8388608;             // [16 bh][64 nt][8 reg][512] K A-frag slots
  u16t* vtg  = ws + 12582912;            // [16 bh][64 nt][8 i][64 d] V i-major tiles
  u16t* ao   = ws + 16777216;            // [16384][256] attn out bf16
  u16t* wqkv = ws + 20971520;            // [768][256]
  u16t* wpb  = ws + 21168128;            // [256][256]

  k_cast_x<<<4096, 256, 0, stream>>>((const float4*)x, xb);
  k_cast_w<<<1024, 256, 0, stream>>>(Wq, Wk, Wv, Wp, wqkv, wpb);
  k_gemm<true><<<dim3(128, 12), 256, 0, stream>>>(xb, wqkv, nullptr, qg, kg, vtg, nullptr, 768);
  k_flash<<<512, 256, 0, stream>>>(qg, kg, vtg, ao);
  k_gemm<false><<<dim3(128, 4), 256, 0, stream>>>(ao, wpb, bp, nullptr, nullptr, nullptr, out, 256);
}

// Round 12
// 107.457 us; speedup vs baseline: 1.1361x; 1.1361x over previous
//
#include <hip/hip_runtime.h>

typedef unsigned short u16t;
typedef unsigned int u32t;
typedef __bf16 bf16x8 __attribute__((ext_vector_type(8)));
typedef float f32x4 __attribute__((ext_vector_type(4)));
typedef float f32x16 __attribute__((ext_vector_type(16)));
typedef unsigned int u32x4 __attribute__((ext_vector_type(4)));
typedef unsigned int u32x2 __attribute__((ext_vector_type(2)));

#define DEV static __device__ __forceinline__

DEV u16t f2bf(float f){
  u32t u = __builtin_bit_cast(u32t, f);
  u += 0x7fffu + ((u >> 16) & 1u);   // RNE
  return (u16t)(u >> 16);
}

DEV u32t cvtpk(float lo, float hi){
  u32t r;
  asm("v_cvt_pk_bf16_f32 %0, %1, %2" : "=v"(r) : "v"(lo), "v"(hi));
  return r;
}

// v_permlane32_swap_b32: a.hi32lanes <-> b.lo32lanes
DEV void plswap(u32t &a, u32t &b){
  asm("v_permlane32_swap_b32 %0, %1" : "+v"(a), "+v"(b));
}

DEV float fexp2(float x){
#if __has_builtin(__builtin_amdgcn_exp2f)
  return __builtin_amdgcn_exp2f(x);
#else
  return exp2f(x);
#endif
}

DEV void gll16(const void* g, void* l){
  __builtin_amdgcn_global_load_lds((const __attribute__((address_space(1))) void*)g,
                                   (__attribute__((address_space(3))) void*)l, 16, 0, 0);
}

DEV f32x4 mfma16(bf16x8 a, bf16x8 b, f32x4 c){
  return __builtin_amdgcn_mfma_f32_16x16x32_bf16(a, b, c, 0, 0, 0);
}

DEV f32x16 mfma32(bf16x8 a, bf16x8 b, f32x16 c){
  return __builtin_amdgcn_mfma_f32_32x32x16_bf16(a, b, c, 0, 0, 0);
}

// ---------------- cast x: fp32 -> bf16 ----------------
__global__ __launch_bounds__(256) void k_cast_x(const float4* __restrict__ x, u16t* __restrict__ xb){
  int idx = blockIdx.x * 256 + threadIdx.x;
  float4 v = x[idx];
  ushort4 o = make_ushort4(f2bf(v.x), f2bf(v.y), f2bf(v.z), f2bf(v.w));
  *(ushort4*)&xb[idx * 4] = o;
}

// ---------------- cast weights; fold 0.125*log2(e) into Wq ----------------
__global__ __launch_bounds__(256) void k_cast_w(const float* __restrict__ Wq, const float* __restrict__ Wk,
                         const float* __restrict__ Wv, const float* __restrict__ Wp,
                         u16t* __restrict__ wqkv, u16t* __restrict__ wp){
  int idx = blockIdx.x * 256 + threadIdx.x;  // 0..262143
  if (idx < 196608){
    float v;
    if (idx < 65536)        v = Wq[idx] * 0.1803368801f;   // 0.125 * log2(e)
    else if (idx < 131072)  v = Wk[idx - 65536];
    else                    v = Wv[idx - 131072];
    wqkv[idx] = f2bf(v);
  } else {
    int j = idx - 196608;
    wp[j] = f2bf(Wp[j]);
  }
}

// ---------------- bf16 GEMM: out[m,n] = sum_k A[m,k]*W[n,k] ----------------
// BM=128, BN=64, BK=64, 4 waves (2x2). LDS 16B-chunk XOR swizzle.
// QKV epilogue: Q -> row-major [bh][n][64];
//   K -> flash A-frag slots: [bh][nt 64][kk*2+jt][hi*32+p] x 16B (slot = K[jt*32+p][kk*16+8hi..+8])
//   V -> i-major tiles [bh][nt][8 i][64 d] x 16B (slot = V^T[d][8i..8i+8])
// Both K and V flash staging sources are perfectly LINEAR.
template<bool IS_QKV>
__global__ __launch_bounds__(256) void k_gemm(const u16t* __restrict__ A, const u16t* __restrict__ W,
    const float* __restrict__ bias, u16t* __restrict__ oq, u16t* __restrict__ okk, u16t* __restrict__ vtg,
    float* __restrict__ op, int Ntot){
  __shared__ u32x4 sm[1536];
  const int tid = threadIdx.x, lane = tid & 63, w = tid >> 6, g = lane >> 4, li = lane & 15;
  const int m0 = blockIdx.x * 128, n0 = blockIdx.y * 64;
  const int wm = w >> 1, wn = w & 1;
  f32x4 acc[4][2] = {};
  for (int kk = 0; kk < 4; ++kk){
    #pragma unroll
    for (int rnd = 0; rnd < 4; ++rnd){
      int cid = rnd * 256 + tid;
      int row = cid >> 3, ch = cid & 7;
      const u16t* src = A + (m0 + row) * 256 + kk * 64 + ((ch ^ (row & 7)) << 3);
      gll16(src, (char*)sm + (rnd * 256 + w * 64) * 16);
    }
    #pragma unroll
    for (int rnd = 0; rnd < 2; ++rnd){
      int cid = rnd * 256 + tid;
      int row = cid >> 3, ch = cid & 7;
      const u16t* src = W + (n0 + row) * 256 + kk * 64 + ((ch ^ (row & 7)) << 3);
      gll16(src, (char*)sm + 16384 + (rnd * 256 + w * 64) * 16);
    }
    __syncthreads();
    #pragma unroll
    for (int ks = 0; ks < 2; ++ks){
      bf16x8 bfr[2];
      #pragma unroll
      for (int nj = 0; nj < 2; ++nj){
        int row = wn * 32 + nj * 16 + li;
        bfr[nj] = __builtin_bit_cast(bf16x8, sm[1024 + row * 8 + ((ks * 4 + g) ^ (row & 7))]);
      }
      #pragma unroll
      for (int mi = 0; mi < 4; ++mi){
        int row = wm * 64 + mi * 16 + li;
        bf16x8 af = __builtin_bit_cast(bf16x8, sm[row * 8 + ((ks * 4 + g) ^ (row & 7))]);
        #pragma unroll
        for (int nj = 0; nj < 2; ++nj)
          acc[mi][nj] = mfma16(af, bfr[nj], acc[mi][nj]);
      }
    }
    __syncthreads();
  }
  if (IS_QKV){
    const int which = n0 >> 8, h = (n0 >> 6) & 3;
    if (which == 2){
      // transpose V within block via LDS (vt[64 d][128 kv-local], chunk-XOR swizzled),
      // then store i-major tiles
      u16t* smv = (u16t*)sm;
      #pragma unroll
      for (int mi = 0; mi < 4; ++mi){
        #pragma unroll
        for (int nj = 0; nj < 2; ++nj){
          int d = wn * 32 + nj * 16 + li;
          int mloc = wm * 64 + mi * 16 + g * 4;
          u32x2 pk2;
          pk2.x = cvtpk(acc[mi][nj][0], acc[mi][nj][1]);
          pk2.y = cvtpk(acc[mi][nj][2], acc[mi][nj][3]);
          int chk = mloc >> 3, inner = (mloc & 7) * 2;
          *(u32x2*)((char*)smv + d * 256 + (((chk ^ (d & 7))) << 4) + inner) = pk2;
        }
      }
      __syncthreads();
      const int b = m0 >> 12, bh2 = b * 4 + h, mbase = m0 & 4095;
      #pragma unroll
      for (int rnd = 0; rnd < 4; ++rnd){
        int qq = rnd * 256 + tid;       // 0..1023
        int d = qq & 63, cidx = qq >> 6;              // cidx 0..15 (8 kv each)
        u32x4 val = *(const u32x4*)((char*)smv + d * 256 + ((cidx ^ (d & 7)) << 4));
        int nt = (mbase >> 6) + (cidx >> 3), i = cidx & 7;
        *(u32x4*)((char*)vtg + ((((size_t)bh2 * 64 + nt) * 8 + i) * 64 + d) * 16) = val;
      }
    } else if (which == 1){
      // K: flash A-frag slot layout
      #pragma unroll
      for (int mi = 0; mi < 4; ++mi){
        int m = m0 + wm * 64 + mi * 16 + g * 4;
        int b = m >> 12;
        #pragma unroll
        for (int nj = 0; nj < 2; ++nj){
          int d = wn * 32 + nj * 16 + li;
          int kk2 = d >> 4, dhi = (d >> 3) & 1, e = d & 7;
          #pragma unroll
          for (int r = 0; r < 4; ++r){
            int row = (m + r) & 4095;
            int nt = row >> 6, jt = (row >> 5) & 1, pp = row & 31;
            okk[(size_t)(b * 4 + h) * 262144 + nt * 4096 + (kk2 * 2 + jt) * 512 + dhi * 256 + pp * 8 + e]
              = f2bf(acc[mi][nj][r]);
          }
        }
      }
    } else {
      // Q: row-major
      #pragma unroll
      for (int mi = 0; mi < 4; ++mi){
        int m = m0 + wm * 64 + mi * 16 + g * 4;
        int b = m >> 12, nn = m & 4095;
        #pragma unroll
        for (int nj = 0; nj < 2; ++nj){
          int d = wn * 32 + nj * 16 + li;
          #pragma unroll
          for (int r = 0; r < 4; ++r)
            oq[((b * 4 + h) * 4096 + nn + r) * 64 + d] = f2bf(acc[mi][nj][r]);
        }
      }
    }
  } else {
    #pragma unroll
    for (int mi = 0; mi < 4; ++mi){
      int m = m0 + wm * 64 + mi * 16 + g * 4;
      #pragma unroll
      for (int nj = 0; nj < 2; ++nj){
        int n = n0 + wn * 32 + nj * 16 + li;
        float bv = bias[n];
        #pragma unroll
        for (int r = 0; r < 4; ++r)
          op[(m + r) * Ntot + n] = acc[mi][nj][r] + bv;
      }
    }
  }
}

// ---------------- flash attention: 8-wave blocks, in-block KV split, shared dbuf LDS ----------------
// 512 blocks = 16 bh x 32 q-tiles(128 rows); 512 threads = 8 waves: wave (kvh=w>>2, qg=w&3)
// handles q-rows qg*32..+32 over KV half kvh (32 tiles of 64). Each half has its own
// shared double-buffered LDS stream (2 x (K 8KB | V 8KB)) staged by its 4 waves.
// m201 discipline: raw s_barrier + counted vmcnt(4); per-thread queue = [t x4][t+1 x4].
// 4096 waves = 4/SIMD (VGPR ~72). Merge of 2 KV-half partials via LDS (no-max softmax).
__global__ __launch_bounds__(512) void k_flash(const u16t* __restrict__ q,
    const u16t* __restrict__ kslot, const u16t* __restrict__ vslot, u16t* __restrict__ ao){
  __shared__ char sm[66560];   // stream h @ h*32768: buf c @ c*16384 (K 8KB | V 8KB); lsums @65536
  const int tid = threadIdx.x, lane = tid & 63, w = tid >> 6;
  const int hi = lane >> 5, p = lane & 31;
  const int kvh = w >> 2, qg = w & 3;
  const int bid = blockIdx.x;
  const int swz = (bid & 7) * 64 + (bid >> 3);    // XCD-aware, bijective (512%8==0)
  const int bh = swz >> 5, qt = swz & 31;
  const int rowbase = qt * 128 + qg * 32;
  const int r256 = tid & 255;
  const char* kbB = (const char*)kslot + (size_t)bh * 524288 + (size_t)kvh * 262144 + r256 * 16;
  const char* vbB = (const char*)vslot + (size_t)bh * 524288 + (size_t)kvh * 262144 + r256 * 16;
  char* myLds = sm + kvh * 32768;

  auto stage = [&](int t, int c){
    char* dst = myLds + c * 16384 + r256 * 16;
    const char* sK = kbB + (size_t)t * 8192;
    const char* sV = vbB + (size_t)t * 8192;
    gll16(sK, dst);
    gll16(sK + 4096, dst + 4096);
    gll16(sV, dst + 8192);
    gll16(sV + 4096, dst + 12288);
  };

  // Q B-frags: qf[kk] = Q[rowbase+p][k=kk*16+8hi+e]
  u32x4 qf[4];
  #pragma unroll
  for (int kk = 0; kk < 4; ++kk)
    qf[kk] = *(const u32x4*)&q[((size_t)bh * 4096 + rowbase + p) * 64 + kk * 16 + hi * 8];
  asm volatile("s_waitcnt vmcnt(0)" ::: "memory");   // clean queue: only gll16 from here
  stage(0, 0);
  stage(1, 1);

  f32x16 ot[2] = {};         // [dt] O^T accum (rows d, cols i=p)
  float lsp[4] = {};
  const f32x16 fz = {};

  #pragma unroll 1
  for (int t = 0; t < 32; ++t){
    asm volatile("s_waitcnt vmcnt(4)" ::: "memory"); // my 4 loads of tile t landed
    __builtin_amdgcn_s_barrier();                    // => whole stream's tile-t loads landed
    asm volatile("" ::: "memory");
    const char* Kb = myLds + (t & 1) * 16384;
    const char* Vt = Kb + 8192;
    // ---- QK: S^T[j=0..63][i=p] ----
    f32x16 st[2];
    #pragma unroll
    for (int kk = 0; kk < 4; ++kk)
      #pragma unroll
      for (int jt = 0; jt < 2; ++jt){
        bf16x8 kf = __builtin_bit_cast(bf16x8,
            *(const u32x4*)(Kb + (kk * 2 + jt) * 1024 + lane * 16));
        st[jt] = mfma32(kf, __builtin_bit_cast(bf16x8, qf[kk]), kk == 0 ? fz : st[jt]);
      }
    // ---- per jt: exp2 + lsum + pack + PV ----
    #pragma unroll
    for (int jt = 0; jt < 2; ++jt){
      float e[16];
      #pragma unroll
      for (int r = 0; r < 16; ++r)
        e[r] = fexp2(st[jt][r]);
      #pragma unroll
      for (int r = 0; r < 16; ++r)
        lsp[r & 3] += e[r];
      u32x4 pf[2];
      #pragma unroll
      for (int s = 0; s < 2; ++s){
        u32t a0 = cvtpk(e[s*8+0], e[s*8+1]);
        u32t a1 = cvtpk(e[s*8+2], e[s*8+3]);
        u32t b0 = cvtpk(e[s*8+4], e[s*8+5]);
        u32t b1 = cvtpk(e[s*8+6], e[s*8+7]);
        plswap(a0, b0);
        plswap(a1, b1);
        pf[s] = (u32x4){a0, a1, b0, b1};
      }
      #pragma unroll
      for (int s = 0; s < 2; ++s)
        #pragma unroll
        for (int dt = 0; dt < 2; ++dt){
          bf16x8 vf = __builtin_bit_cast(bf16x8,
              *(const u32x4*)(Vt + ((jt * 2 + s) * 2 + hi) * 1024 + dt * 512 + p * 16));
          ot[dt] = mfma32(vf, __builtin_bit_cast(bf16x8, pf[s]), ot[dt]);
        }
    }
    asm volatile("s_waitcnt lgkmcnt(0)" ::: "memory"); // all my LDS reads of tile t retired
    __builtin_amdgcn_s_barrier();                      // => whole block done reading buf t&1
    asm volatile("" ::: "memory");
    stage((t + 2) & 31, t & 1);                        // overwrite the buffer just consumed
  }
  asm volatile("s_waitcnt vmcnt(0)" ::: "memory");     // drain tail dummy stages
  __builtin_amdgcn_s_barrier();                        // before reusing LDS for merge
  asm volatile("" ::: "memory");

  // lsum: lane (p,hi) summed its j-subset; fold hi-halves -> row-sum for i=p over half kvh
  float l = (lsp[0] + lsp[1]) + (lsp[2] + lsp[3]);
  l += __shfl_xor(l, 32);
  float* lsums = (float*)(sm + 65536);                 // [8 waves][32 q]
  if (lane < 32) lsums[w * 32 + lane] = l;

  // write own O^T partial as f32 [32 q][64 d] into region w*8192 (quad-XOR swizzle)
  {
    char* reg = sm + w * 8192;
    #pragma unroll
    for (int dt = 0; dt < 2; ++dt)
      #pragma unroll
      for (int s4 = 0; s4 < 4; ++s4){
        f32x4 v4 = {ot[dt][4*s4+0], ot[dt][4*s4+1], ot[dt][4*s4+2], ot[dt][4*s4+3]};
        int quad = 2 * s4 + hi + 8 * dt;               // d = 4*quad .. +4
        *(f32x4*)(reg + p * 256 + ((quad ^ (p & 15)) << 4)) = v4;
      }
  }
  __syncthreads();

  // merge 2 KV-half partials + store: thread -> (q-row 0..127, 16-d segment 0..3)
  {
    const int qrow = tid >> 2, seg = tid & 3;
    const int qg2 = qrow >> 5, qloc = qrow & 31;
    float ltot = lsums[qg2 * 32 + qloc] + lsums[(4 + qg2) * 32 + qloc];
    float inv = __builtin_amdgcn_rcpf(ltot);
    const int b = bh >> 2, head = bh & 3;
    u32t pko[8];
    #pragma unroll
    for (int k = 0; k < 4; ++k){
      int quad = seg * 4 + k;
      int off = qloc * 256 + ((quad ^ (qloc & 15)) << 4);
      f32x4 s = *(const f32x4*)(sm + qg2 * 8192 + off)
              + *(const f32x4*)(sm + (4 + qg2) * 8192 + off);
      s = s * inv;
      pko[2*k]   = cvtpk(s[0], s[1]);
      pko[2*k+1] = cvtpk(s[2], s[3]);
    }
    u16t* dst = ao + ((size_t)b * 4096 + qt * 128 + qrow) * 256 + head * 64 + seg * 16;
    *(u32x4*)(dst)     = (u32x4){pko[0], pko[1], pko[2], pko[3]};
    *(u32x4*)(dst + 8) = (u32x4){pko[4], pko[5], pko[6], pko[7]};
  }
}

extern "C" void kernel_launch(void* const* d_in, const int* in_sizes, int n_in,
                              void* d_out, int out_size, void* d_ws, size_t ws_size,
                              hipStream_t stream){
  (void)in_sizes; (void)n_in; (void)out_size; (void)ws_size;
  const float* x  = (const float*)d_in[0];
  const float* Wq = (const float*)d_in[1];
  const float* Wk = (const float*)d_in[2];
  const float* Wv = (const float*)d_in[3];
  const float* Wp = (const float*)d_in[4];
  const float* bp = (const float*)d_in[5];
  float* out = (float*)d_out;

  u16t* ws   = (u16t*)d_ws;
  u16t* xb   = ws;                       // [16384][256] bf16 x
  u16t* qg   = ws + 4194304;             // [16 bh][4096][64] Q row-major
  u16t* kg   = ws + 8388608;             // [16 bh][64 nt][8 reg][512] K A-frag slots
  u16t* vtg  = ws + 12582912;            // [16 bh][64 nt][8 i][64 d] V i-major tiles
  u16t* ao   = ws + 16777216;            // [16384][256] attn out bf16
  u16t* wqkv = ws + 20971520;            // [768][256]
  u16t* wpb  = ws + 21168128;            // [256][256]

  k_cast_x<<<4096, 256, 0, stream>>>((const float4*)x, xb);
  k_cast_w<<<1024, 256, 0, stream>>>(Wq, Wk, Wv, Wp, wqkv, wpb);
  k_gemm<true><<<dim3(128, 12), 256, 0, stream>>>(xb, wqkv, nullptr, qg, kg, vtg, nullptr, 768);
  k_flash<<<512, 512, 0, stream>>>(qg, kg, vtg, ao);
  k_gemm<false><<<dim3(128, 4), 256, 0, stream>>>(ao, wpb, bp, nullptr, nullptr, nullptr, out, 256);
}